// Round 5
// baseline (148.160 us; speedup 1.0000x reference)
//
#include <hip/hip_runtime.h>

// Embedding gather: out[t, :] = w[x[t], :]
// x: (8*2048,) int32, w: (50257, 512) f32, out: (8*2048, 512) f32.
// Pure memory-bound copy; vectorize as 16 B/lane native vectors.
// Each 64-lane wave handles 64 consecutive 16B-chunks = half a row, so the
// token index load is wave-uniform (single broadcast from cache).

typedef float f32x4 __attribute__((ext_vector_type(4)));

constexpr int EMBED  = 512;
constexpr int COLS4  = EMBED / 4;   // 128 x 16B chunks per row

__global__ __launch_bounds__(256) void embed_gather_kernel(
    const int* __restrict__ x,
    const f32x4* __restrict__ w4,
    f32x4* __restrict__ out4,
    int n_tok)
{
    long long gid = (long long)blockIdx.x * blockDim.x + threadIdx.x;
    long long total = (long long)n_tok * COLS4;
    if (gid >= total) return;

    int tok = (int)(gid >> 7);      // gid / 128  -> token index
    int col = (int)(gid & (COLS4 - 1));

    int row = x[tok];               // wave-uniform broadcast

    f32x4 v = w4[(long long)row * COLS4 + col];
    // Output is never re-read: bypass cache so w rows stay resident in L2/L3.
    __builtin_nontemporal_store(v, &out4[gid]);
}

extern "C" void kernel_launch(void* const* d_in, const int* in_sizes, int n_in,
                              void* d_out, int out_size, void* d_ws, size_t ws_size,
                              hipStream_t stream) {
    const int*    x = (const int*)d_in[0];     // (8, 2048) int32
    const float*  w = (const float*)d_in[1];   // (50257, 512) f32
    float*      out = (float*)d_out;           // (8, 2048, 512) f32

    int n_tok = in_sizes[0];                   // 16384
    long long total4 = (long long)n_tok * COLS4;

    int block = 256;
    int grid  = (int)((total4 + block - 1) / block);  // 8192

    embed_gather_kernel<<<grid, block, 0, stream>>>(
        x, reinterpret_cast<const f32x4*>(w),
        reinterpret_cast<f32x4*>(out), n_tok);
}

// Round 7
// 147.209 us; speedup vs baseline: 1.0065x; 1.0065x over previous
//
#include <hip/hip_runtime.h>

// Embedding gather: out[t, :] = w[x[t], :]
// x: (8*2048,) int32, w: (50257, 512) f32, out: (8*2048, 512) f32.
// Pure memory-bound copy; 16 B/lane stride-1 vectors (the m13-verified
// 6.3 TB/s access pattern). Each 64-lane wave covers half a row, so the
// token index load is wave-uniform (single broadcast from cache).
//
// R5->R6: dropped __builtin_nontemporal_store — nt is unquantified on
// gfx950 and regular stores can't hurt: w (103 MB) exceeds L2 regardless,
// and L3 (256 MB) holds w + out together.

typedef float f32x4 __attribute__((ext_vector_type(4)));

constexpr int EMBED  = 512;
constexpr int COLS4  = EMBED / 4;   // 128 x 16B chunks per row

__global__ __launch_bounds__(256) void embed_gather_kernel(
    const int* __restrict__ x,
    const f32x4* __restrict__ w4,
    f32x4* __restrict__ out4,
    int n_tok)
{
    long long gid = (long long)blockIdx.x * blockDim.x + threadIdx.x;
    long long total = (long long)n_tok * COLS4;
    if (gid >= total) return;

    int tok = (int)(gid >> 7);      // gid / 128  -> token index
    int col = (int)(gid & (COLS4 - 1));

    int row = x[tok];               // wave-uniform broadcast

    out4[gid] = w4[(long long)row * COLS4 + col];
}

extern "C" void kernel_launch(void* const* d_in, const int* in_sizes, int n_in,
                              void* d_out, int out_size, void* d_ws, size_t ws_size,
                              hipStream_t stream) {
    const int*    x = (const int*)d_in[0];     // (8, 2048) int32
    const float*  w = (const float*)d_in[1];   // (50257, 512) f32
    float*      out = (float*)d_out;           // (8, 2048, 512) f32

    int n_tok = in_sizes[0];                   // 16384
    long long total4 = (long long)n_tok * COLS4;

    int block = 256;
    int grid  = (int)((total4 + block - 1) / block);  // 8192

    embed_gather_kernel<<<grid, block, 0, stream>>>(
        x, reinterpret_cast<const f32x4*>(w),
        reinterpret_cast<f32x4*>(out), n_tok);
}